// Round 9
// baseline (391.447 us; speedup 1.0000x reference)
//
#include <hip/hip_runtime.h>

typedef unsigned int u32;
typedef unsigned short u16;
typedef short bf16x8 __attribute__((ext_vector_type(8)));
typedef float f32x4 __attribute__((ext_vector_type(4)));
typedef float f32x2 __attribute__((ext_vector_type(2)));
typedef u32 u32x4 __attribute__((ext_vector_type(4)));

#define HBLK 512  // blocks in hist/scatter2 pass (R25: 2 blocks/CU = full 32 waves/CU)
#define PCAP 2560 // scatter3 LDS part-window capacity (bucket max ~2210 for this input)

__device__ __forceinline__ u16 f2bf(float f) {
  u32 u = __float_as_uint(f);
  u = (u + 0x7FFFu + ((u >> 16) & 1u)) >> 16;
  return (u16)u;
}
__device__ __forceinline__ float bf2f(u32 h) { return __uint_as_float(h << 16); }

// ---------------- CSR build: bucket sort by dst (R21 structure) ----------------
// bucket = dst >> 7 (128 nodes per bucket). Law from R22/R23 failures: per-edge
// GLOBAL atomics & scattered 4B writes cost ~100-150us (cross-XCD line thrash);
// per-block LDS aggregation + block-contiguous writes is the only fast pattern.
// boff row-major (boff[blk*1024+i]): block-owned contiguous row, coalesced.
__global__ void hist_wprep_kernel(const int* __restrict__ dst, int* __restrict__ boff,
                                  int* __restrict__ btotal, int E, int nbuk, int chunk,
                                  const float* __restrict__ W2l, const float* __restrict__ W2r,
                                  const float* __restrict__ W3l, const float* __restrict__ W3r,
                                  u16* __restrict__ wt2, u16* __restrict__ wt3,
                                  const int* __restrict__ batch, int* __restrict__ gcnt, int n) {
  int tid = threadIdx.x;
  // --- wprep part (first 65536 global thread ids pack the two weight mats) ---
  int idx = blockIdx.x * 1024 + tid;
  if (idx < 65536) {
    int which = idx >> 15, r = idx & 32767;
    int j = r >> 8, k = r & 255;
    if (which == 0) {
      float v = (k < 128) ? W2l[k * 128 + j] : W2r[(k - 128) * 128 + j];
      wt2[r] = f2bf(v);
    } else {
      float v = (k < 128) ? W3l[k * 128 + j] : W3r[(k - 128) * 128 + j];
      wt3[r] = f2bf(v);
    }
  }
  // --- hist part (edges by dst-bucket) + batch histogram (nodes by graph) ---
  __shared__ int h[1024];
  __shared__ int gh[64];
  for (int i = tid; i < nbuk; i += 1024) h[i] = 0;
  if (tid < 64) gh[tid] = 0;
  __syncthreads();
  int b0 = blockIdx.x * chunk, b1 = min(b0 + chunk, E);
  int len = max(b1 - b0, 0);
  int ng = len >> 2;
  for (int g4 = tid; g4 < ng; g4 += 1024) {
    u32x4 d4 = *(const u32x4*)(dst + b0 + g4 * 4);
#pragma unroll
    for (int w = 0; w < 4; ++w) atomicAdd(&h[(int)d4[w] >> 7], 1);
  }
  for (int e = b0 + ng * 4 + tid; e < b1; e += 1024)
    atomicAdd(&h[dst[e] >> 7], 1);
  int chunkN = (n + HBLK - 1) / HBLK;
  int n0 = blockIdx.x * chunkN, n1 = min(n0 + chunkN, n);
  for (int i = n0 + tid; i < n1; i += 1024)
    atomicAdd(&gh[batch[i]], 1);
  __syncthreads();
  // row-major boff: block's own contiguous row, coalesced
  for (int i = tid; i < nbuk; i += 1024)
    boff[blockIdx.x * 1024 + i] = atomicAdd(&btotal[i], h[i]);
  if (tid < 64 && gh[tid] > 0)
    atomicAdd(&gcnt[tid], gh[tid]);
}

// partition edges into bucket-ordered part[]: packed (dstLow7<<25 | src).
// 1024 threads, 1-entry-per-thread Hillis-Steele (nbuk=782), dwordx4 reads.
__global__ void scatter2_kernel(const int* __restrict__ src, const int* __restrict__ dst,
                                const int* __restrict__ btotal, const int* __restrict__ boff,
                                u32* __restrict__ part, int* __restrict__ bbase,
                                int E, int nbuk, int chunk) {
  __shared__ int wsum[1024];
  __shared__ int cur[1024];
  int tid = threadIdx.x;
  int v = (tid < nbuk) ? btotal[tid] : 0;
  wsum[tid] = v;
  __syncthreads();
  for (int off = 1; off < 1024; off <<= 1) {
    int t = (tid >= off) ? wsum[tid - off] : 0;
    __syncthreads();
    wsum[tid] += t;
    __syncthreads();
  }
  int excl = wsum[tid] - v;  // exclusive bucket base
  if (tid < nbuk) {
    cur[tid] = excl + boff[blockIdx.x * 1024 + tid];
    if (blockIdx.x == 0) bbase[tid] = excl;  // publish for scatter3
  }
  __syncthreads();
  int b0 = blockIdx.x * chunk, b1 = min(b0 + chunk, E);
  int len = max(b1 - b0, 0);
  int ng = len >> 2;
  for (int g4 = tid; g4 < ng; g4 += 1024) {
    int e = b0 + g4 * 4;
    u32x4 s4 = *(const u32x4*)(src + e);
    u32x4 d4 = *(const u32x4*)(dst + e);
#pragma unroll
    for (int w = 0; w < 4; ++w) {
      int d = (int)d4[w];
      int pos = atomicAdd(&cur[d >> 7], 1);
      part[pos] = s4[w] | ((u32)(d & 127) << 25);
    }
  }
  for (int e = b0 + ng * 4 + tid; e < b1; e += 1024) {
    int d = dst[e];
    int pos = atomicAdd(&cur[d >> 7], 1);
    part[pos] = (u32)src[e] | ((u32)(d & 127) << 25);
  }
}

// per-bucket: count per node, scan -> roff, scatter src into contiguous csr window,
// accumulate x[src] -> mean, fused layer 1. part window staged in LDS once
// (<=PCAP entries; guarded global fallback).
__global__ void scatter3_kernel(const u32* __restrict__ part, const int* __restrict__ bbase,
                                const float* __restrict__ x,
                                const float* __restrict__ W1l, const float* __restrict__ W1r,
                                const float* __restrict__ b1,
                                int* __restrict__ roff, int* __restrict__ csr,
                                u32* __restrict__ h1, int E, int nbuk, int n) {
  int b = blockIdx.x;
  int tid = threadIdx.x;
  int base = bbase[b];
  int end = (b + 1 < nbuk) ? bbase[b + 1] : E;
  int len = end - base;
  int cap = min(len, PCAP);
  __shared__ u32 plds[PCAP];
  __shared__ int cnt[128];
  __shared__ int s[128];
  __shared__ int cur[128];
  __shared__ float xsum[128];
  __shared__ float meanv[128];
  __shared__ float wlA[128], wrA[128], bA[128];
  if (tid < 128) {
    cnt[tid] = 0; xsum[tid] = 0.f;
    wlA[tid] = W1l[tid]; wrA[tid] = W1r[tid]; bA[tid] = b1[tid];
  }
  for (int e = tid; e < cap; e += 512) plds[e] = part[base + e];
  __syncthreads();
  for (int e = tid; e < len; e += 512) {
    u32 p = (e < cap) ? plds[e] : part[base + e];
    atomicAdd(&cnt[p >> 25], 1);
  }
  __syncthreads();
  if (tid < 128) s[tid] = cnt[tid];
  __syncthreads();
  for (int off = 1; off < 128; off <<= 1) {
    int t = (tid >= off && tid < 128) ? s[tid - off] : 0;
    __syncthreads();
    if (tid < 128) s[tid] += t;
    __syncthreads();
  }
  if (tid < 128) {
    int excl = s[tid] - cnt[tid];
    cur[tid] = base + excl;
    int node = b * 128 + tid;
    if (node < n) roff[node] = base + excl;
  }
  if (b == 0 && tid == 0) roff[n] = E;
  __syncthreads();
  for (int e = tid; e < len; e += 512) {
    u32 p = (e < cap) ? plds[e] : part[base + e];
    int sidx = (int)(p & 0x1FFFFFFu);
    int pos = atomicAdd(&cur[p >> 25], 1);
    csr[pos] = sidx;
    atomicAdd(&xsum[p >> 25], x[sidx]);
  }
  __syncthreads();
  if (tid < 128) meanv[tid] = xsum[tid] / (float)max(cnt[tid], 1);
  __syncthreads();
  int nlocal = min(128, n - b * 128);
  for (int q = tid; q < nlocal * 64; q += 512) {
    int ln = q >> 6, w = q & 63;
    int node = b * 128 + ln;
    int j0 = w * 2;
    float m = meanv[ln], xs = x[node];
    float v0 = fmaxf(m * wlA[j0] + xs * wrA[j0] + bA[j0], 0.f);
    float v1 = fmaxf(m * wlA[j0 + 1] + xs * wrA[j0 + 1] + bA[j0 + 1], 0.f);
    h1[(size_t)node * 64 + w] = (u32)f2bf(v0) | ((u32)f2bf(v1) << 16);
  }
}

// ---------------- mean aggregation over CSR (R1 proven: one row / 16-lane group) ----------------
// 57.6 us @ 3.58 TB/s L2-miss BW -- pattern ceiling for random 256B gathers
// (confirmed 7x across structural variants).
__device__ __forceinline__ u32x4 grow(const u32* hp, int s) {
  return *(const u32x4*)(hp + (size_t)s * 64);
}
__device__ __forceinline__ void acc_row(f32x2* a, u32x4 v) {
#pragma unroll
  for (int w = 0; w < 4; ++w)
    a[w] += (f32x2){bf2f(v[w] & 0xFFFFu), bf2f(v[w] >> 16)};
}

__global__ void agg_kernel(const int* __restrict__ csr, const int* __restrict__ roff,
                           const u32* __restrict__ hin, u32* __restrict__ outv, int n) {
  int g = threadIdx.x >> 4, li = threadIdx.x & 15;
  int i = blockIdx.x * 16 + g;
  if (i >= n) return;
  int e0 = roff[i], e1 = roff[i + 1];
  f32x2 a[4] = {};
  const u32* hp = hin + li * 4;  // lane-fixed 16B column within each 256B row
  int e = e0;
  // 8-deep main loop: 8 x 256B gathers in flight per group before any use
  for (; e + 7 < e1; e += 8) {
    int s0 = csr[e], s1 = csr[e + 1], s2 = csr[e + 2], s3 = csr[e + 3];
    int s4 = csr[e + 4], s5 = csr[e + 5], s6 = csr[e + 6], s7 = csr[e + 7];
    u32x4 v0 = grow(hp, s0), v1 = grow(hp, s1), v2 = grow(hp, s2), v3 = grow(hp, s3);
    u32x4 v4 = grow(hp, s4), v5 = grow(hp, s5), v6 = grow(hp, s6), v7 = grow(hp, s7);
    acc_row(a, v0); acc_row(a, v1); acc_row(a, v2); acc_row(a, v3);
    acc_row(a, v4); acc_row(a, v5); acc_row(a, v6); acc_row(a, v7);
  }
  for (; e + 3 < e1; e += 4) {
    int s0 = csr[e], s1 = csr[e + 1], s2 = csr[e + 2], s3 = csr[e + 3];
    u32x4 v0 = grow(hp, s0), v1 = grow(hp, s1), v2 = grow(hp, s2), v3 = grow(hp, s3);
    acc_row(a, v0); acc_row(a, v1); acc_row(a, v2); acc_row(a, v3);
  }
  for (; e < e1; ++e) acc_row(a, grow(hp, csr[e]));
  float inv = 1.f / (float)max(e1 - e0, 1);
  u32x4 o;
#pragma unroll
  for (int w = 0; w < 4; ++w)
    o[w] = (u32)f2bf(a[w].x * inv) | ((u32)f2bf(a[w].y * inv) << 16);
  *(u32x4*)(outv + (size_t)i * 64 + li * 4) = o;
}

// h_next = relu([mean | h] @ [Wl; Wr] + b), MFMA 16x16x32 bf16.
// Weights staged in LDS (XOR-swizzled, conflict-free ds_read_b128).
// Epilogue: C staged into the (now dead) weight LDS with padded row stride
// (136 u16 -> <=2-way bank aliasing).
// MODE 0: coalesced dwordx4 write-back of h_next (R16 proven).
// MODE 1 (layer 3): h3 never hits global -- per-column segmented sums over the
// staged C tile + atomicAdd into pooled (R20 proven). R25: log-softmax head
// fused via last-block-done pattern (deletes the head dispatch + gap); the
// last-arriving block reads pooled/gcnt with agent-scope atomic loads (G16
// coherence) and writes the 640 logits.
template <int MODE>
__launch_bounds__(512)
__global__ void mm_kernel(const u16* Aleft, const u16* Aright,
                          const u16* __restrict__ Wt, const float* __restrict__ bias,
                          u16* Out, const int* __restrict__ batch,
                          float* __restrict__ pooled, int* __restrict__ done,
                          const int* __restrict__ gcnt,
                          const float* __restrict__ Wfc, const float* __restrict__ bfc,
                          float* __restrict__ out, int n) {
  __shared__ __align__(16) u16 wlds[32768];  // 64 KB: weights -> C staging -> head scratch
  __shared__ int bgp[128];
  for (int c = threadIdx.x; c < 4096; c += 512) {
    int j = c >> 5, ch = c & 31;
    int swz = ch ^ (j & 31);
    *(u32x4*)(&wlds[j * 256 + swz * 8]) = *(const u32x4*)(&Wt[j * 256 + ch * 8]);
  }
  __syncthreads();
  int wave = threadIdx.x >> 6;
  int lane = threadIdx.x & 63;
  int quad = lane >> 4, l16 = lane & 15;
  int row0 = blockIdx.x * 128 + wave * 16;
  int m = row0 + l16;
  int mc = m < n ? m : (n - 1);
  f32x4 acc[8] = {};
  const u16* Ah[2] = {Aleft, Aright};
#pragma unroll
  for (int half = 0; half < 2; ++half) {
    const u16* A = Ah[half] + (size_t)mc * 128;
#pragma unroll
    for (int s = 0; s < 4; ++s) {
      bf16x8 a = *(const bf16x8*)(A + s * 32 + quad * 8);  // A[m][k], k = s*32+quad*8+j
      int chunk = (half << 4) + (s << 2) + quad;
#pragma unroll
      for (int t = 0; t < 8; ++t) {
        int j = t * 16 + l16;
        int swz = chunk ^ (j & 31);
        bf16x8 b = *(const bf16x8*)(&wlds[j * 256 + swz * 8]);  // B[k][j] = Wt[j][k]
        acc[t] = __builtin_amdgcn_mfma_f32_16x16x32_bf16(a, b, acc[t], 0, 0, 0);
      }
    }
  }
  // C layout: col = lane&15, row = quad*4 + reg (m89-verified)
  // ---- epilogue: bias+relu+bf16 -> LDS staging (stride 136 u16) ----
  __syncthreads();  // all weight reads done; wlds reusable
  int rl_base = wave * 16 + quad * 4;  // local row base of this lane's outputs
#pragma unroll
  for (int t = 0; t < 8; ++t) {
    int j = t * 16 + l16;
    float bj = bias[j];
#pragma unroll
    for (int r = 0; r < 4; ++r) {
      float v = acc[t][r] + bj;
      wlds[(rl_base + r) * 136 + j] = f2bf(fmaxf(v, 0.f));
    }
  }
  if (MODE == 1) {
    if (threadIdx.x < 128) {
      int rr = blockIdx.x * 128 + threadIdx.x;
      bgp[threadIdx.x] = (rr < n) ? batch[rr] : -1;
    }
  }
  __syncthreads();
  if (MODE == 0) {
    // ---- coalesced write-back: 128 rows x 16 chunks of 16B, 4 rounds ----
    int base_row = blockIdx.x * 128;
    for (int q = 0; q < 4; ++q) {
      int idx = q * 512 + threadIdx.x;  // 0..2047
      int rl = idx >> 4;                // 0..127
      int ch = idx & 15;                // 16B chunk within 256B row
      int mr = base_row + rl;
      if (mr < n)
        *(u32x4*)(&Out[(size_t)mr * 128 + ch * 8]) =
            *(const u32x4*)(&wlds[rl * 136 + ch * 8]);
    }
  } else {
    // ---- fused global_mean_pool: batch sorted -> per-column segmented sums.
    int tcol = threadIdx.x & 127, seg = threadIdx.x >> 7;  // 4 segs x 32 rows
    float accp = 0.f;
    int gcur = -1;
    for (int r = seg * 32; r < seg * 32 + 32; ++r) {
      int gb = bgp[r];
      if (gb != gcur) {
        if (gcur >= 0) atomicAdd(&pooled[gcur * 128 + tcol], accp);
        gcur = gb;
        accp = 0.f;
      }
      if (gb >= 0) accp += bf2f((u32)wlds[r * 136 + tcol]);
    }
    if (gcur >= 0) atomicAdd(&pooled[gcur * 128 + tcol], accp);
    // ---- fused head: last-arriving block computes log-softmax logits ----
    __threadfence();  // make this block's pooled atomics globally visible
    __shared__ int lastBlk;
    if (threadIdx.x == 0) {
      int t = atomicAdd(done, 1);
      lastBlk = (t == (int)gridDim.x - 1) ? 1 : 0;
    }
    __syncthreads();
    if (!lastBlk) return;
    float* plds = (float*)wlds;   // 8192 floats = 32KB (C tile dead)
    float* lg = plds + 8192;      // 640 floats
    __shared__ float ginv[64];
    for (int i = threadIdx.x; i < 8192; i += 512)
      plds[i] = __hip_atomic_load(&pooled[i], __ATOMIC_RELAXED, __HIP_MEMORY_SCOPE_AGENT);
    if (threadIdx.x < 64) {
      int gc = __hip_atomic_load(&gcnt[threadIdx.x], __ATOMIC_RELAXED, __HIP_MEMORY_SCOPE_AGENT);
      ginv[threadIdx.x] = 1.f / (float)max(gc, 1);
    }
    __syncthreads();
    for (int t = threadIdx.x; t < 640; t += 512) {
      int g = t / 10, c = t % 10;
      float acc2 = bfc[c];
      float inv = ginv[g];
      for (int k = 0; k < 128; ++k) acc2 += plds[g * 128 + k] * inv * Wfc[k * 10 + c];
      lg[t] = acc2;
    }
    __syncthreads();
    for (int t = threadIdx.x; t < 640; t += 512) {
      int g = t / 10, c = t % 10;
      float mx = -1e30f;
      for (int q = 0; q < 10; ++q) mx = fmaxf(mx, lg[g * 10 + q]);
      float se = 0.f;
      for (int q = 0; q < 10; ++q) se += expf(lg[g * 10 + q] - mx);
      out[g * 10 + c] = lg[g * 10 + c] - mx - logf(se);
    }
  }
}

extern "C" void kernel_launch(void* const* d_in, const int* in_sizes, int n_in,
                              void* d_out, int out_size, void* d_ws, size_t ws_size,
                              hipStream_t stream) {
  const float* x   = (const float*)d_in[0];
  const int* ei    = (const int*)d_in[1];
  const int* batch = (const int*)d_in[2];
  const float* W1l = (const float*)d_in[3];
  const float* W1r = (const float*)d_in[4];
  const float* b1  = (const float*)d_in[5];
  const float* W2l = (const float*)d_in[6];
  const float* W2r = (const float*)d_in[7];
  const float* b2  = (const float*)d_in[8];
  const float* W3l = (const float*)d_in[9];
  const float* W3r = (const float*)d_in[10];
  const float* b3  = (const float*)d_in[11];
  const float* Wfc = (const float*)d_in[12];
  const float* bfc = (const float*)d_in[13];
  float* out = (float*)d_out;
  int N = in_sizes[0];
  int E = in_sizes[1] / 2;
  const int* src = ei;
  const int* dst = ei + E;

  char* p = (char*)d_ws;
  auto alloc = [&](size_t bytes) { void* r = (void*)p; p += (bytes + 255) & ~(size_t)255; return r; };
  int* roff   = (int*)alloc((size_t)(N + 1) * 4);
  int* csr    = (int*)alloc((size_t)E * 4);
  u32* bufA   = (u32*)alloc((size_t)N * 64 * 4);  // h1 -> mean3 (aliases boff early)
  u32* bufB   = (u32*)alloc((size_t)N * 64 * 4);  // mean2 -> h2 (aliases part early)
  u16* wt2    = (u16*)alloc(32768 * 2);
  u16* wt3    = (u16*)alloc(32768 * 2);
  // pooled/gcnt/btotal/done contiguous -> single memset below
  float* pooled = (float*)alloc(64 * 128 * 4);    // 32768 B
  int* gcnt   = (int*)alloc(64 * 4);              // 256 B
  int* btotal = (int*)alloc(1024 * 4);            // 4096 B
  int* done   = (int*)alloc(256);                 // 256 B
  int* bbase  = (int*)alloc(1024 * 4);

  // CSR-build-time aliases (boff read only by scatter2; scatter3 writes h1
  // into bufA but reads only bbase/part/x -> no clobber hazard)
  int nbuk = (N + 127) >> 7;          // 782
  int* boff = (int*)bufA;             // HBLK rows x 1024 ints = 2 MB (row-major)
  u32* part = (u32*)bufB;             // E u32 = 6.4 MB
  int chunk = (((E + HBLK - 1) / HBLK) + 3) & ~3;  // 16B-aligned block windows

  hipMemsetAsync(pooled, 0, 32768 + 256 + 4096 + 256, stream);  // pooled+gcnt+btotal+done
  hist_wprep_kernel<<<HBLK, 1024, 0, stream>>>(dst, boff, btotal, E, nbuk, chunk,
                                               W2l, W2r, W3l, W3r, wt2, wt3,
                                               batch, gcnt, N);
  scatter2_kernel<<<HBLK, 1024, 0, stream>>>(src, dst, btotal, boff, part, bbase,
                                             E, nbuk, chunk);
  scatter3_kernel<<<nbuk, 512, 0, stream>>>(part, bbase, x, W1l, W1r, b1,
                                            roff, csr, bufA, E, nbuk, N);
  // layer 2: mean2 = agg(h1); h2 = relu([mean2|h1]W2 + b2) written to bufB
  agg_kernel<<<(N + 15) / 16, 256, 0, stream>>>(csr, roff, bufA, bufB, N);
  mm_kernel<0><<<(N + 127) / 128, 512, 0, stream>>>((const u16*)bufB, (const u16*)bufA,
                                                    wt2, b2, (u16*)bufB, batch, pooled,
                                                    done, gcnt, Wfc, bfc, out, N);
  // layer 3: mean3 = agg(h2); h3 -> pooled directly; last block computes head
  agg_kernel<<<(N + 15) / 16, 256, 0, stream>>>(csr, roff, bufB, bufA, N);
  mm_kernel<1><<<(N + 127) / 128, 512, 0, stream>>>((const u16*)bufA, (const u16*)bufB,
                                                    wt3, b3, (u16*)bufA, batch, pooled,
                                                    done, gcnt, Wfc, bfc, out, N);
}

// Round 10
// 303.690 us; speedup vs baseline: 1.2890x; 1.2890x over previous
//
#include <hip/hip_runtime.h>

typedef unsigned int u32;
typedef unsigned short u16;
typedef short bf16x8 __attribute__((ext_vector_type(8)));
typedef float f32x4 __attribute__((ext_vector_type(4)));
typedef float f32x2 __attribute__((ext_vector_type(2)));
typedef u32 u32x4 __attribute__((ext_vector_type(4)));

#define HBLK 512  // blocks in hist/scatter2 (R25-proven: 2 blocks/CU, ~-13us vs 256)
#define PCAP 2560 // scatter3 LDS part-window capacity (bucket max ~2210 for this input)

__device__ __forceinline__ u16 f2bf(float f) {
  u32 u = __float_as_uint(f);
  u = (u + 0x7FFFu + ((u >> 16) & 1u)) >> 16;
  return (u16)u;
}
__device__ __forceinline__ float bf2f(u32 h) { return __uint_as_float(h << 16); }

// ---------------- CSR build: bucket sort by dst (R21 structure) ----------------
// bucket = dst >> 7 (128 nodes per bucket). Laws learned R22/R23/R25:
//  - per-edge GLOBAL atomics / scattered 4B writes: ~100-150us cross-XCD thrash
//  - __threadfence() (agent release fence) forces an L2 writeback per block on
//    non-coherent XCD L2s: ~105us across a grid. NEVER use in hot kernels.
//  - fast pattern: per-block LDS aggregation + block-contiguous global writes.
// boff row-major (boff[blk*1024+i]): block-owned contiguous row, coalesced.
__global__ void hist_wprep_kernel(const int* __restrict__ dst, int* __restrict__ boff,
                                  int* __restrict__ btotal, int E, int nbuk, int chunk,
                                  const float* __restrict__ W2l, const float* __restrict__ W2r,
                                  const float* __restrict__ W3l, const float* __restrict__ W3r,
                                  u16* __restrict__ wt2, u16* __restrict__ wt3,
                                  const int* __restrict__ batch, int* __restrict__ gcnt, int n) {
  int tid = threadIdx.x;
  // --- wprep part (first 65536 global thread ids pack the two weight mats) ---
  int idx = blockIdx.x * 1024 + tid;
  if (idx < 65536) {
    int which = idx >> 15, r = idx & 32767;
    int j = r >> 8, k = r & 255;
    if (which == 0) {
      float v = (k < 128) ? W2l[k * 128 + j] : W2r[(k - 128) * 128 + j];
      wt2[r] = f2bf(v);
    } else {
      float v = (k < 128) ? W3l[k * 128 + j] : W3r[(k - 128) * 128 + j];
      wt3[r] = f2bf(v);
    }
  }
  // --- hist part (edges by dst-bucket) + batch histogram (nodes by graph) ---
  __shared__ int h[1024];
  __shared__ int gh[64];
  for (int i = tid; i < nbuk; i += 1024) h[i] = 0;
  if (tid < 64) gh[tid] = 0;
  __syncthreads();
  int b0 = blockIdx.x * chunk, b1 = min(b0 + chunk, E);
  int len = max(b1 - b0, 0);
  int ng = len >> 2;
  for (int g4 = tid; g4 < ng; g4 += 1024) {
    u32x4 d4 = *(const u32x4*)(dst + b0 + g4 * 4);
#pragma unroll
    for (int w = 0; w < 4; ++w) atomicAdd(&h[(int)d4[w] >> 7], 1);
  }
  for (int e = b0 + ng * 4 + tid; e < b1; e += 1024)
    atomicAdd(&h[dst[e] >> 7], 1);
  int chunkN = (n + HBLK - 1) / HBLK;
  int n0 = blockIdx.x * chunkN, n1 = min(n0 + chunkN, n);
  for (int i = n0 + tid; i < n1; i += 1024)
    atomicAdd(&gh[batch[i]], 1);
  __syncthreads();
  // row-major boff: block's own contiguous row, coalesced
  for (int i = tid; i < nbuk; i += 1024)
    boff[blockIdx.x * 1024 + i] = atomicAdd(&btotal[i], h[i]);
  if (tid < 64 && gh[tid] > 0)
    atomicAdd(&gcnt[tid], gh[tid]);
}

// partition edges into bucket-ordered part[]: packed (dstLow7<<25 | src).
// 1024 threads, 1-entry-per-thread Hillis-Steele (nbuk=782), dwordx4 reads.
__global__ void scatter2_kernel(const int* __restrict__ src, const int* __restrict__ dst,
                                const int* __restrict__ btotal, const int* __restrict__ boff,
                                u32* __restrict__ part, int* __restrict__ bbase,
                                int E, int nbuk, int chunk) {
  __shared__ int wsum[1024];
  __shared__ int cur[1024];
  int tid = threadIdx.x;
  int v = (tid < nbuk) ? btotal[tid] : 0;
  wsum[tid] = v;
  __syncthreads();
  for (int off = 1; off < 1024; off <<= 1) {
    int t = (tid >= off) ? wsum[tid - off] : 0;
    __syncthreads();
    wsum[tid] += t;
    __syncthreads();
  }
  int excl = wsum[tid] - v;  // exclusive bucket base
  if (tid < nbuk) {
    cur[tid] = excl + boff[blockIdx.x * 1024 + tid];
    if (blockIdx.x == 0) bbase[tid] = excl;  // publish for scatter3
  }
  __syncthreads();
  int b0 = blockIdx.x * chunk, b1 = min(b0 + chunk, E);
  int len = max(b1 - b0, 0);
  int ng = len >> 2;
  for (int g4 = tid; g4 < ng; g4 += 1024) {
    int e = b0 + g4 * 4;
    u32x4 s4 = *(const u32x4*)(src + e);
    u32x4 d4 = *(const u32x4*)(dst + e);
#pragma unroll
    for (int w = 0; w < 4; ++w) {
      int d = (int)d4[w];
      int pos = atomicAdd(&cur[d >> 7], 1);
      part[pos] = s4[w] | ((u32)(d & 127) << 25);
    }
  }
  for (int e = b0 + ng * 4 + tid; e < b1; e += 1024) {
    int d = dst[e];
    int pos = atomicAdd(&cur[d >> 7], 1);
    part[pos] = (u32)src[e] | ((u32)(d & 127) << 25);
  }
}

// per-bucket: count per node, scan -> roff, scatter src into contiguous csr window,
// accumulate x[src] -> mean, fused layer 1. part window staged in LDS once
// (<=PCAP entries; guarded global fallback).
__global__ void scatter3_kernel(const u32* __restrict__ part, const int* __restrict__ bbase,
                                const float* __restrict__ x,
                                const float* __restrict__ W1l, const float* __restrict__ W1r,
                                const float* __restrict__ b1,
                                int* __restrict__ roff, int* __restrict__ csr,
                                u32* __restrict__ h1, int E, int nbuk, int n) {
  int b = blockIdx.x;
  int tid = threadIdx.x;
  int base = bbase[b];
  int end = (b + 1 < nbuk) ? bbase[b + 1] : E;
  int len = end - base;
  int cap = min(len, PCAP);
  __shared__ u32 plds[PCAP];
  __shared__ int cnt[128];
  __shared__ int s[128];
  __shared__ int cur[128];
  __shared__ float xsum[128];
  __shared__ float meanv[128];
  __shared__ float wlA[128], wrA[128], bA[128];
  if (tid < 128) {
    cnt[tid] = 0; xsum[tid] = 0.f;
    wlA[tid] = W1l[tid]; wrA[tid] = W1r[tid]; bA[tid] = b1[tid];
  }
  for (int e = tid; e < cap; e += 512) plds[e] = part[base + e];
  __syncthreads();
  for (int e = tid; e < len; e += 512) {
    u32 p = (e < cap) ? plds[e] : part[base + e];
    atomicAdd(&cnt[p >> 25], 1);
  }
  __syncthreads();
  if (tid < 128) s[tid] = cnt[tid];
  __syncthreads();
  for (int off = 1; off < 128; off <<= 1) {
    int t = (tid >= off && tid < 128) ? s[tid - off] : 0;
    __syncthreads();
    if (tid < 128) s[tid] += t;
    __syncthreads();
  }
  if (tid < 128) {
    int excl = s[tid] - cnt[tid];
    cur[tid] = base + excl;
    int node = b * 128 + tid;
    if (node < n) roff[node] = base + excl;
  }
  if (b == 0 && tid == 0) roff[n] = E;
  __syncthreads();
  for (int e = tid; e < len; e += 512) {
    u32 p = (e < cap) ? plds[e] : part[base + e];
    int sidx = (int)(p & 0x1FFFFFFu);
    int pos = atomicAdd(&cur[p >> 25], 1);
    csr[pos] = sidx;
    atomicAdd(&xsum[p >> 25], x[sidx]);
  }
  __syncthreads();
  if (tid < 128) meanv[tid] = xsum[tid] / (float)max(cnt[tid], 1);
  __syncthreads();
  int nlocal = min(128, n - b * 128);
  for (int q = tid; q < nlocal * 64; q += 512) {
    int ln = q >> 6, w = q & 63;
    int node = b * 128 + ln;
    int j0 = w * 2;
    float m = meanv[ln], xs = x[node];
    float v0 = fmaxf(m * wlA[j0] + xs * wrA[j0] + bA[j0], 0.f);
    float v1 = fmaxf(m * wlA[j0 + 1] + xs * wrA[j0 + 1] + bA[j0 + 1], 0.f);
    h1[(size_t)node * 64 + w] = (u32)f2bf(v0) | ((u32)f2bf(v1) << 16);
  }
}

// ---------------- mean aggregation over CSR (R1 proven: one row / 16-lane group) ----------------
// 57.6 us @ 3.58 TB/s L2-miss BW -- pattern ceiling for random 256B gathers
// (confirmed 8x across structural variants).
__device__ __forceinline__ u32x4 grow(const u32* hp, int s) {
  return *(const u32x4*)(hp + (size_t)s * 64);
}
__device__ __forceinline__ void acc_row(f32x2* a, u32x4 v) {
#pragma unroll
  for (int w = 0; w < 4; ++w)
    a[w] += (f32x2){bf2f(v[w] & 0xFFFFu), bf2f(v[w] >> 16)};
}

__global__ void agg_kernel(const int* __restrict__ csr, const int* __restrict__ roff,
                           const u32* __restrict__ hin, u32* __restrict__ outv, int n) {
  int g = threadIdx.x >> 4, li = threadIdx.x & 15;
  int i = blockIdx.x * 16 + g;
  if (i >= n) return;
  int e0 = roff[i], e1 = roff[i + 1];
  f32x2 a[4] = {};
  const u32* hp = hin + li * 4;  // lane-fixed 16B column within each 256B row
  int e = e0;
  // 8-deep main loop: 8 x 256B gathers in flight per group before any use
  for (; e + 7 < e1; e += 8) {
    int s0 = csr[e], s1 = csr[e + 1], s2 = csr[e + 2], s3 = csr[e + 3];
    int s4 = csr[e + 4], s5 = csr[e + 5], s6 = csr[e + 6], s7 = csr[e + 7];
    u32x4 v0 = grow(hp, s0), v1 = grow(hp, s1), v2 = grow(hp, s2), v3 = grow(hp, s3);
    u32x4 v4 = grow(hp, s4), v5 = grow(hp, s5), v6 = grow(hp, s6), v7 = grow(hp, s7);
    acc_row(a, v0); acc_row(a, v1); acc_row(a, v2); acc_row(a, v3);
    acc_row(a, v4); acc_row(a, v5); acc_row(a, v6); acc_row(a, v7);
  }
  for (; e + 3 < e1; e += 4) {
    int s0 = csr[e], s1 = csr[e + 1], s2 = csr[e + 2], s3 = csr[e + 3];
    u32x4 v0 = grow(hp, s0), v1 = grow(hp, s1), v2 = grow(hp, s2), v3 = grow(hp, s3);
    acc_row(a, v0); acc_row(a, v1); acc_row(a, v2); acc_row(a, v3);
  }
  for (; e < e1; ++e) acc_row(a, grow(hp, csr[e]));
  float inv = 1.f / (float)max(e1 - e0, 1);
  u32x4 o;
#pragma unroll
  for (int w = 0; w < 4; ++w)
    o[w] = (u32)f2bf(a[w].x * inv) | ((u32)f2bf(a[w].y * inv) << 16);
  *(u32x4*)(outv + (size_t)i * 64 + li * 4) = o;
}

// h_next = relu([mean | h] @ [Wl; Wr] + b), MFMA 16x16x32 bf16.
// Weights staged in LDS (XOR-swizzled, conflict-free ds_read_b128).
// Epilogue: C staged into the (now dead) weight LDS with padded row stride
// (136 u16 -> <=2-way bank aliasing).
// MODE 0: coalesced dwordx4 write-back of h_next (R16 proven).
// MODE 1 (layer 3): h3 never hits global -- per-column segmented sums over the
// staged C tile + atomicAdd into pooled (R20 proven). Head stays a separate
// kernel: R25 showed fusing it (threadfence + ticket) costs ~105us of L2
// writeback stalls on non-coherent XCD L2s.
template <int MODE>
__launch_bounds__(512)
__global__ void mm_kernel(const u16* Aleft, const u16* Aright,
                          const u16* __restrict__ Wt, const float* __restrict__ bias,
                          u16* Out, const int* __restrict__ batch,
                          float* __restrict__ pooled, int n) {
  __shared__ u16 wlds[32768];  // 64 KB: weights, then reused for C staging
  __shared__ int bgp[128];
  for (int c = threadIdx.x; c < 4096; c += 512) {
    int j = c >> 5, ch = c & 31;
    int swz = ch ^ (j & 31);
    *(u32x4*)(&wlds[j * 256 + swz * 8]) = *(const u32x4*)(&Wt[j * 256 + ch * 8]);
  }
  __syncthreads();
  int wave = threadIdx.x >> 6;
  int lane = threadIdx.x & 63;
  int quad = lane >> 4, l16 = lane & 15;
  int row0 = blockIdx.x * 128 + wave * 16;
  int m = row0 + l16;
  int mc = m < n ? m : (n - 1);
  f32x4 acc[8] = {};
  const u16* Ah[2] = {Aleft, Aright};
#pragma unroll
  for (int half = 0; half < 2; ++half) {
    const u16* A = Ah[half] + (size_t)mc * 128;
#pragma unroll
    for (int s = 0; s < 4; ++s) {
      bf16x8 a = *(const bf16x8*)(A + s * 32 + quad * 8);  // A[m][k], k = s*32+quad*8+j
      int chunk = (half << 4) + (s << 2) + quad;
#pragma unroll
      for (int t = 0; t < 8; ++t) {
        int j = t * 16 + l16;
        int swz = chunk ^ (j & 31);
        bf16x8 b = *(const bf16x8*)(&wlds[j * 256 + swz * 8]);  // B[k][j] = Wt[j][k]
        acc[t] = __builtin_amdgcn_mfma_f32_16x16x32_bf16(a, b, acc[t], 0, 0, 0);
      }
    }
  }
  // C layout: col = lane&15, row = quad*4 + reg (m89-verified)
  // ---- epilogue: bias+relu+bf16 -> LDS staging (stride 136 u16) ----
  __syncthreads();  // all weight reads done; wlds reusable
  int rl_base = wave * 16 + quad * 4;  // local row base of this lane's outputs
#pragma unroll
  for (int t = 0; t < 8; ++t) {
    int j = t * 16 + l16;
    float bj = bias[j];
#pragma unroll
    for (int r = 0; r < 4; ++r) {
      float v = acc[t][r] + bj;
      wlds[(rl_base + r) * 136 + j] = f2bf(fmaxf(v, 0.f));
    }
  }
  if (MODE == 1) {
    if (threadIdx.x < 128) {
      int rr = blockIdx.x * 128 + threadIdx.x;
      bgp[threadIdx.x] = (rr < n) ? batch[rr] : -1;
    }
  }
  __syncthreads();
  if (MODE == 0) {
    // ---- coalesced write-back: 128 rows x 16 chunks of 16B, 4 rounds ----
    int base_row = blockIdx.x * 128;
    for (int q = 0; q < 4; ++q) {
      int idx = q * 512 + threadIdx.x;  // 0..2047
      int rl = idx >> 4;                // 0..127
      int ch = idx & 15;                // 16B chunk within 256B row
      int mr = base_row + rl;
      if (mr < n)
        *(u32x4*)(&Out[(size_t)mr * 128 + ch * 8]) =
            *(const u32x4*)(&wlds[rl * 136 + ch * 8]);
    }
  } else {
    // ---- fused global_mean_pool: batch sorted -> per-column segmented sums.
    int tcol = threadIdx.x & 127, seg = threadIdx.x >> 7;  // 4 segs x 32 rows
    float accp = 0.f;
    int gcur = -1;
    for (int r = seg * 32; r < seg * 32 + 32; ++r) {
      int gb = bgp[r];
      if (gb != gcur) {
        if (gcur >= 0) atomicAdd(&pooled[gcur * 128 + tcol], accp);
        gcur = gb;
        accp = 0.f;
      }
      if (gb >= 0) accp += bf2f((u32)wlds[r * 136 + tcol]);
    }
    if (gcur >= 0) atomicAdd(&pooled[gcur * 128 + tcol], accp);
  }
}

__global__ void head_kernel(const float* __restrict__ pooled, const int* __restrict__ gcnt,
                            const float* __restrict__ Wfc, const float* __restrict__ bfc,
                            float* __restrict__ out) {
  __shared__ float lg[64][10];
  int t = threadIdx.x;
  if (t < 640) {
    int g = t / 10, c = t % 10;
    float inv = 1.f / (float)max(gcnt[g], 1);
    float acc = bfc[c];
    for (int k = 0; k < 128; ++k) acc += pooled[g * 128 + k] * inv * Wfc[k * 10 + c];
    lg[g][c] = acc;
  }
  __syncthreads();
  if (t < 640) {
    int g = t / 10, c = t % 10;
    float mx = -1e30f;
    for (int q = 0; q < 10; ++q) mx = fmaxf(mx, lg[g][q]);
    float se = 0.f;
    for (int q = 0; q < 10; ++q) se += expf(lg[g][q] - mx);
    out[g * 10 + c] = lg[g][c] - mx - logf(se);
  }
}

extern "C" void kernel_launch(void* const* d_in, const int* in_sizes, int n_in,
                              void* d_out, int out_size, void* d_ws, size_t ws_size,
                              hipStream_t stream) {
  const float* x   = (const float*)d_in[0];
  const int* ei    = (const int*)d_in[1];
  const int* batch = (const int*)d_in[2];
  const float* W1l = (const float*)d_in[3];
  const float* W1r = (const float*)d_in[4];
  const float* b1  = (const float*)d_in[5];
  const float* W2l = (const float*)d_in[6];
  const float* W2r = (const float*)d_in[7];
  const float* b2  = (const float*)d_in[8];
  const float* W3l = (const float*)d_in[9];
  const float* W3r = (const float*)d_in[10];
  const float* b3  = (const float*)d_in[11];
  const float* Wfc = (const float*)d_in[12];
  const float* bfc = (const float*)d_in[13];
  float* out = (float*)d_out;
  int N = in_sizes[0];
  int E = in_sizes[1] / 2;
  const int* src = ei;
  const int* dst = ei + E;

  char* p = (char*)d_ws;
  auto alloc = [&](size_t bytes) { void* r = (void*)p; p += (bytes + 255) & ~(size_t)255; return r; };
  int* roff   = (int*)alloc((size_t)(N + 1) * 4);
  int* csr    = (int*)alloc((size_t)E * 4);
  u32* bufA   = (u32*)alloc((size_t)N * 64 * 4);  // h1 -> mean3 (aliases boff early)
  u32* bufB   = (u32*)alloc((size_t)N * 64 * 4);  // mean2 -> h2 (aliases part early)
  u16* wt2    = (u16*)alloc(32768 * 2);
  u16* wt3    = (u16*)alloc(32768 * 2);
  // pooled/gcnt/btotal contiguous -> single memset below
  float* pooled = (float*)alloc(64 * 128 * 4);    // 32768 B
  int* gcnt   = (int*)alloc(64 * 4);              // 256 B
  int* btotal = (int*)alloc(1024 * 4);            // 4096 B
  int* bbase  = (int*)alloc(1024 * 4);

  // CSR-build-time aliases (boff read only by scatter2; scatter3 writes h1
  // into bufA but reads only bbase/part/x -> no clobber hazard)
  int nbuk = (N + 127) >> 7;          // 782
  int* boff = (int*)bufA;             // HBLK rows x 1024 ints = 2 MB (row-major)
  u32* part = (u32*)bufB;             // E u32 = 6.4 MB
  int chunk = (((E + HBLK - 1) / HBLK) + 3) & ~3;  // 16B-aligned block windows

  hipMemsetAsync(pooled, 0, 32768 + 256 + 4096, stream);  // pooled+gcnt+btotal
  hist_wprep_kernel<<<HBLK, 1024, 0, stream>>>(dst, boff, btotal, E, nbuk, chunk,
                                               W2l, W2r, W3l, W3r, wt2, wt3,
                                               batch, gcnt, N);
  scatter2_kernel<<<HBLK, 1024, 0, stream>>>(src, dst, btotal, boff, part, bbase,
                                             E, nbuk, chunk);
  scatter3_kernel<<<nbuk, 512, 0, stream>>>(part, bbase, x, W1l, W1r, b1,
                                            roff, csr, bufA, E, nbuk, N);
  // layer 2: mean2 = agg(h1); h2 = relu([mean2|h1]W2 + b2) written to bufB
  agg_kernel<<<(N + 15) / 16, 256, 0, stream>>>(csr, roff, bufA, bufB, N);
  mm_kernel<0><<<(N + 127) / 128, 512, 0, stream>>>((const u16*)bufB, (const u16*)bufA,
                                                    wt2, b2, (u16*)bufB, batch, pooled, N);
  // layer 3: mean3 = agg(h2); h3 -> pooled directly (never hits global)
  agg_kernel<<<(N + 15) / 16, 256, 0, stream>>>(csr, roff, bufB, bufA, N);
  mm_kernel<1><<<(N + 127) / 128, 512, 0, stream>>>((const u16*)bufA, (const u16*)bufB,
                                                    wt3, b3, (u16*)bufA, batch, pooled, N);
  head_kernel<<<1, 640, 0, stream>>>(pooled, gcnt, Wfc, bfc, out);
}

// Round 11
// 297.792 us; speedup vs baseline: 1.3145x; 1.0198x over previous
//
#include <hip/hip_runtime.h>

typedef unsigned int u32;
typedef unsigned short u16;
typedef short bf16x8 __attribute__((ext_vector_type(8)));
typedef float f32x4 __attribute__((ext_vector_type(4)));
typedef float f32x2 __attribute__((ext_vector_type(2)));
typedef u32 u32x4 __attribute__((ext_vector_type(4)));

#define HBLK 256  // blocks in hist/scatter2 (R26 A/B: 512 costs ~5us -> 256 final)
#define PCAP 2560 // scatter3 LDS part-window capacity (bucket max ~2210 for this input)

__device__ __forceinline__ u16 f2bf(float f) {
  u32 u = __float_as_uint(f);
  u = (u + 0x7FFFu + ((u >> 16) & 1u)) >> 16;
  return (u16)u;
}
__device__ __forceinline__ float bf2f(u32 h) { return __uint_as_float(h << 16); }

// ---------------- CSR build: bucket sort by dst (R24-final) ----------------
// bucket = dst >> 7 (128 nodes per bucket). Session laws (R22/R23/R25/R26):
//  - per-edge GLOBAL atomics / scattered 4B writes: ~100-150us cross-XCD thrash
//  - __threadfence() in a hot kernel: ~105us of L2 writebacks (non-coherent XCDs)
//  - fast pattern: per-block LDS aggregation + block-contiguous global writes
//  - HBLK=256 (1 block/CU, 16 waves) beats 512 (part[] scatter granularity halves)
__global__ void hist_wprep_kernel(const int* __restrict__ dst, int* __restrict__ boff,
                                  int* __restrict__ btotal, int E, int nbuk, int chunk,
                                  const float* __restrict__ W2l, const float* __restrict__ W2r,
                                  const float* __restrict__ W3l, const float* __restrict__ W3r,
                                  u16* __restrict__ wt2, u16* __restrict__ wt3,
                                  const int* __restrict__ batch, int* __restrict__ gcnt, int n) {
  int tid = threadIdx.x;
  // --- wprep part (first 65536 global thread ids pack the two weight mats) ---
  int idx = blockIdx.x * 1024 + tid;
  if (idx < 65536) {
    int which = idx >> 15, r = idx & 32767;
    int j = r >> 8, k = r & 255;
    if (which == 0) {
      float v = (k < 128) ? W2l[k * 128 + j] : W2r[(k - 128) * 128 + j];
      wt2[r] = f2bf(v);
    } else {
      float v = (k < 128) ? W3l[k * 128 + j] : W3r[(k - 128) * 128 + j];
      wt3[r] = f2bf(v);
    }
  }
  // --- hist part (edges by dst-bucket) + batch histogram (nodes by graph) ---
  __shared__ int h[1024];
  __shared__ int gh[64];
  for (int i = tid; i < nbuk; i += 1024) h[i] = 0;
  if (tid < 64) gh[tid] = 0;
  __syncthreads();
  int b0 = blockIdx.x * chunk, b1 = min(b0 + chunk, E);
  int len = max(b1 - b0, 0);
  int ng = len >> 2;
  for (int g4 = tid; g4 < ng; g4 += 1024) {
    u32x4 d4 = *(const u32x4*)(dst + b0 + g4 * 4);
#pragma unroll
    for (int w = 0; w < 4; ++w) atomicAdd(&h[(int)d4[w] >> 7], 1);
  }
  for (int e = b0 + ng * 4 + tid; e < b1; e += 1024)
    atomicAdd(&h[dst[e] >> 7], 1);
  int chunkN = (n + HBLK - 1) / HBLK;
  int n0 = blockIdx.x * chunkN, n1 = min(n0 + chunkN, n);
  for (int i = n0 + tid; i < n1; i += 1024)
    atomicAdd(&gh[batch[i]], 1);
  __syncthreads();
  // row-major boff: block's own contiguous row, coalesced
  for (int i = tid; i < nbuk; i += 1024)
    boff[blockIdx.x * 1024 + i] = atomicAdd(&btotal[i], h[i]);
  if (tid < 64 && gh[tid] > 0)
    atomicAdd(&gcnt[tid], gh[tid]);
}

// partition edges into bucket-ordered part[]: packed (dstLow7<<25 | src).
// 1024 threads, 1-entry-per-thread Hillis-Steele (nbuk=782), dwordx4 reads.
__global__ void scatter2_kernel(const int* __restrict__ src, const int* __restrict__ dst,
                                const int* __restrict__ btotal, const int* __restrict__ boff,
                                u32* __restrict__ part, int* __restrict__ bbase,
                                int E, int nbuk, int chunk) {
  __shared__ int wsum[1024];
  __shared__ int cur[1024];
  int tid = threadIdx.x;
  int v = (tid < nbuk) ? btotal[tid] : 0;
  wsum[tid] = v;
  __syncthreads();
  for (int off = 1; off < 1024; off <<= 1) {
    int t = (tid >= off) ? wsum[tid - off] : 0;
    __syncthreads();
    wsum[tid] += t;
    __syncthreads();
  }
  int excl = wsum[tid] - v;  // exclusive bucket base
  if (tid < nbuk) {
    cur[tid] = excl + boff[blockIdx.x * 1024 + tid];
    if (blockIdx.x == 0) bbase[tid] = excl;  // publish for scatter3
  }
  __syncthreads();
  int b0 = blockIdx.x * chunk, b1 = min(b0 + chunk, E);
  int len = max(b1 - b0, 0);
  int ng = len >> 2;
  for (int g4 = tid; g4 < ng; g4 += 1024) {
    int e = b0 + g4 * 4;
    u32x4 s4 = *(const u32x4*)(src + e);
    u32x4 d4 = *(const u32x4*)(dst + e);
#pragma unroll
    for (int w = 0; w < 4; ++w) {
      int d = (int)d4[w];
      int pos = atomicAdd(&cur[d >> 7], 1);
      part[pos] = s4[w] | ((u32)(d & 127) << 25);
    }
  }
  for (int e = b0 + ng * 4 + tid; e < b1; e += 1024) {
    int d = dst[e];
    int pos = atomicAdd(&cur[d >> 7], 1);
    part[pos] = (u32)src[e] | ((u32)(d & 127) << 25);
  }
}

// per-bucket: count per node, scan -> roff, scatter src into contiguous csr window,
// accumulate x[src] -> mean, fused layer 1. part window staged in LDS once
// (<=PCAP entries; guarded global fallback).
__global__ void scatter3_kernel(const u32* __restrict__ part, const int* __restrict__ bbase,
                                const float* __restrict__ x,
                                const float* __restrict__ W1l, const float* __restrict__ W1r,
                                const float* __restrict__ b1,
                                int* __restrict__ roff, int* __restrict__ csr,
                                u32* __restrict__ h1, int E, int nbuk, int n) {
  int b = blockIdx.x;
  int tid = threadIdx.x;
  int base = bbase[b];
  int end = (b + 1 < nbuk) ? bbase[b + 1] : E;
  int len = end - base;
  int cap = min(len, PCAP);
  __shared__ u32 plds[PCAP];
  __shared__ int cnt[128];
  __shared__ int s[128];
  __shared__ int cur[128];
  __shared__ float xsum[128];
  __shared__ float meanv[128];
  __shared__ float wlA[128], wrA[128], bA[128];
  if (tid < 128) {
    cnt[tid] = 0; xsum[tid] = 0.f;
    wlA[tid] = W1l[tid]; wrA[tid] = W1r[tid]; bA[tid] = b1[tid];
  }
  for (int e = tid; e < cap; e += 512) plds[e] = part[base + e];
  __syncthreads();
  for (int e = tid; e < len; e += 512) {
    u32 p = (e < cap) ? plds[e] : part[base + e];
    atomicAdd(&cnt[p >> 25], 1);
  }
  __syncthreads();
  if (tid < 128) s[tid] = cnt[tid];
  __syncthreads();
  for (int off = 1; off < 128; off <<= 1) {
    int t = (tid >= off && tid < 128) ? s[tid - off] : 0;
    __syncthreads();
    if (tid < 128) s[tid] += t;
    __syncthreads();
  }
  if (tid < 128) {
    int excl = s[tid] - cnt[tid];
    cur[tid] = base + excl;
    int node = b * 128 + tid;
    if (node < n) roff[node] = base + excl;
  }
  if (b == 0 && tid == 0) roff[n] = E;
  __syncthreads();
  for (int e = tid; e < len; e += 512) {
    u32 p = (e < cap) ? plds[e] : part[base + e];
    int sidx = (int)(p & 0x1FFFFFFu);
    int pos = atomicAdd(&cur[p >> 25], 1);
    csr[pos] = sidx;
    atomicAdd(&xsum[p >> 25], x[sidx]);
  }
  __syncthreads();
  if (tid < 128) meanv[tid] = xsum[tid] / (float)max(cnt[tid], 1);
  __syncthreads();
  int nlocal = min(128, n - b * 128);
  for (int q = tid; q < nlocal * 64; q += 512) {
    int ln = q >> 6, w = q & 63;
    int node = b * 128 + ln;
    int j0 = w * 2;
    float m = meanv[ln], xs = x[node];
    float v0 = fmaxf(m * wlA[j0] + xs * wrA[j0] + bA[j0], 0.f);
    float v1 = fmaxf(m * wlA[j0 + 1] + xs * wrA[j0 + 1] + bA[j0 + 1], 0.f);
    h1[(size_t)node * 64 + w] = (u32)f2bf(v0) | ((u32)f2bf(v1) << 16);
  }
}

// ---------------- mean aggregation over CSR (R1 proven: one row / 16-lane group) ----------------
// 58 us @ 3.55 TB/s. FETCH 176.7 MB == information-theoretic minimum:
// per XCD, distinct neighbor rows ~= N*(1-e^-2) ~= 86.5k x 256B ~= 22.1 MB x 8
// non-coherent L2 domains = 177 MB. Zero redundant fetch; rate = random-256B
// HBM granule ceiling (confirmed 8x across occupancy/structure variants).
__device__ __forceinline__ u32x4 grow(const u32* hp, int s) {
  return *(const u32x4*)(hp + (size_t)s * 64);
}
__device__ __forceinline__ void acc_row(f32x2* a, u32x4 v) {
#pragma unroll
  for (int w = 0; w < 4; ++w)
    a[w] += (f32x2){bf2f(v[w] & 0xFFFFu), bf2f(v[w] >> 16)};
}

__global__ void agg_kernel(const int* __restrict__ csr, const int* __restrict__ roff,
                           const u32* __restrict__ hin, u32* __restrict__ outv, int n) {
  int g = threadIdx.x >> 4, li = threadIdx.x & 15;
  int i = blockIdx.x * 16 + g;
  if (i >= n) return;
  int e0 = roff[i], e1 = roff[i + 1];
  f32x2 a[4] = {};
  const u32* hp = hin + li * 4;  // lane-fixed 16B column within each 256B row
  int e = e0;
  // 8-deep main loop: 8 x 256B gathers in flight per group before any use
  for (; e + 7 < e1; e += 8) {
    int s0 = csr[e], s1 = csr[e + 1], s2 = csr[e + 2], s3 = csr[e + 3];
    int s4 = csr[e + 4], s5 = csr[e + 5], s6 = csr[e + 6], s7 = csr[e + 7];
    u32x4 v0 = grow(hp, s0), v1 = grow(hp, s1), v2 = grow(hp, s2), v3 = grow(hp, s3);
    u32x4 v4 = grow(hp, s4), v5 = grow(hp, s5), v6 = grow(hp, s6), v7 = grow(hp, s7);
    acc_row(a, v0); acc_row(a, v1); acc_row(a, v2); acc_row(a, v3);
    acc_row(a, v4); acc_row(a, v5); acc_row(a, v6); acc_row(a, v7);
  }
  for (; e + 3 < e1; e += 4) {
    int s0 = csr[e], s1 = csr[e + 1], s2 = csr[e + 2], s3 = csr[e + 3];
    u32x4 v0 = grow(hp, s0), v1 = grow(hp, s1), v2 = grow(hp, s2), v3 = grow(hp, s3);
    acc_row(a, v0); acc_row(a, v1); acc_row(a, v2); acc_row(a, v3);
  }
  for (; e < e1; ++e) acc_row(a, grow(hp, csr[e]));
  float inv = 1.f / (float)max(e1 - e0, 1);
  u32x4 o;
#pragma unroll
  for (int w = 0; w < 4; ++w)
    o[w] = (u32)f2bf(a[w].x * inv) | ((u32)f2bf(a[w].y * inv) << 16);
  *(u32x4*)(outv + (size_t)i * 64 + li * 4) = o;
}

// h_next = relu([mean | h] @ [Wl; Wr] + b), MFMA 16x16x32 bf16.
// Weights staged in LDS (XOR-swizzled, conflict-free ds_read_b128).
// Epilogue: C staged into the (now dead) weight LDS with padded row stride
// (136 u16 -> <=2-way bank aliasing).
// MODE 0: coalesced dwordx4 write-back of h_next (R16 proven).
// MODE 1 (layer 3): h3 never hits global -- per-column segmented sums over the
// staged C tile + atomicAdd into pooled (R20 proven). Head stays a separate
// kernel (R25: fusing costs ~105us of L2 writeback on non-coherent XCD L2s).
template <int MODE>
__launch_bounds__(512)
__global__ void mm_kernel(const u16* Aleft, const u16* Aright,
                          const u16* __restrict__ Wt, const float* __restrict__ bias,
                          u16* Out, const int* __restrict__ batch,
                          float* __restrict__ pooled, int n) {
  __shared__ u16 wlds[32768];  // 64 KB: weights, then reused for C staging
  __shared__ int bgp[128];
  for (int c = threadIdx.x; c < 4096; c += 512) {
    int j = c >> 5, ch = c & 31;
    int swz = ch ^ (j & 31);
    *(u32x4*)(&wlds[j * 256 + swz * 8]) = *(const u32x4*)(&Wt[j * 256 + ch * 8]);
  }
  __syncthreads();
  int wave = threadIdx.x >> 6;
  int lane = threadIdx.x & 63;
  int quad = lane >> 4, l16 = lane & 15;
  int row0 = blockIdx.x * 128 + wave * 16;
  int m = row0 + l16;
  int mc = m < n ? m : (n - 1);
  f32x4 acc[8] = {};
  const u16* Ah[2] = {Aleft, Aright};
#pragma unroll
  for (int half = 0; half < 2; ++half) {
    const u16* A = Ah[half] + (size_t)mc * 128;
#pragma unroll
    for (int s = 0; s < 4; ++s) {
      bf16x8 a = *(const bf16x8*)(A + s * 32 + quad * 8);  // A[m][k], k = s*32+quad*8+j
      int chunk = (half << 4) + (s << 2) + quad;
#pragma unroll
      for (int t = 0; t < 8; ++t) {
        int j = t * 16 + l16;
        int swz = chunk ^ (j & 31);
        bf16x8 b = *(const bf16x8*)(&wlds[j * 256 + swz * 8]);  // B[k][j] = Wt[j][k]
        acc[t] = __builtin_amdgcn_mfma_f32_16x16x32_bf16(a, b, acc[t], 0, 0, 0);
      }
    }
  }
  // C layout: col = lane&15, row = quad*4 + reg (m89-verified)
  // ---- epilogue: bias+relu+bf16 -> LDS staging (stride 136 u16) ----
  __syncthreads();  // all weight reads done; wlds reusable
  int rl_base = wave * 16 + quad * 4;  // local row base of this lane's outputs
#pragma unroll
  for (int t = 0; t < 8; ++t) {
    int j = t * 16 + l16;
    float bj = bias[j];
#pragma unroll
    for (int r = 0; r < 4; ++r) {
      float v = acc[t][r] + bj;
      wlds[(rl_base + r) * 136 + j] = f2bf(fmaxf(v, 0.f));
    }
  }
  if (MODE == 1) {
    if (threadIdx.x < 128) {
      int rr = blockIdx.x * 128 + threadIdx.x;
      bgp[threadIdx.x] = (rr < n) ? batch[rr] : -1;
    }
  }
  __syncthreads();
  if (MODE == 0) {
    // ---- coalesced write-back: 128 rows x 16 chunks of 16B, 4 rounds ----
    int base_row = blockIdx.x * 128;
    for (int q = 0; q < 4; ++q) {
      int idx = q * 512 + threadIdx.x;  // 0..2047
      int rl = idx >> 4;                // 0..127
      int ch = idx & 15;                // 16B chunk within 256B row
      int mr = base_row + rl;
      if (mr < n)
        *(u32x4*)(&Out[(size_t)mr * 128 + ch * 8]) =
            *(const u32x4*)(&wlds[rl * 136 + ch * 8]);
    }
  } else {
    // ---- fused global_mean_pool: batch sorted -> per-column segmented sums.
    int tcol = threadIdx.x & 127, seg = threadIdx.x >> 7;  // 4 segs x 32 rows
    float accp = 0.f;
    int gcur = -1;
    for (int r = seg * 32; r < seg * 32 + 32; ++r) {
      int gb = bgp[r];
      if (gb != gcur) {
        if (gcur >= 0) atomicAdd(&pooled[gcur * 128 + tcol], accp);
        gcur = gb;
        accp = 0.f;
      }
      if (gb >= 0) accp += bf2f((u32)wlds[r * 136 + tcol]);
    }
    if (gcur >= 0) atomicAdd(&pooled[gcur * 128 + tcol], accp);
  }
}

__global__ void head_kernel(const float* __restrict__ pooled, const int* __restrict__ gcnt,
                            const float* __restrict__ Wfc, const float* __restrict__ bfc,
                            float* __restrict__ out) {
  __shared__ float lg[64][10];
  int t = threadIdx.x;
  if (t < 640) {
    int g = t / 10, c = t % 10;
    float inv = 1.f / (float)max(gcnt[g], 1);
    float acc = bfc[c];
    for (int k = 0; k < 128; ++k) acc += pooled[g * 128 + k] * inv * Wfc[k * 10 + c];
    lg[g][c] = acc;
  }
  __syncthreads();
  if (t < 640) {
    int g = t / 10, c = t % 10;
    float mx = -1e30f;
    for (int q = 0; q < 10; ++q) mx = fmaxf(mx, lg[g][q]);
    float se = 0.f;
    for (int q = 0; q < 10; ++q) se += expf(lg[g][q] - mx);
    out[g * 10 + c] = lg[g][c] - mx - logf(se);
  }
}

extern "C" void kernel_launch(void* const* d_in, const int* in_sizes, int n_in,
                              void* d_out, int out_size, void* d_ws, size_t ws_size,
                              hipStream_t stream) {
  const float* x   = (const float*)d_in[0];
  const int* ei    = (const int*)d_in[1];
  const int* batch = (const int*)d_in[2];
  const float* W1l = (const float*)d_in[3];
  const float* W1r = (const float*)d_in[4];
  const float* b1  = (const float*)d_in[5];
  const float* W2l = (const float*)d_in[6];
  const float* W2r = (const float*)d_in[7];
  const float* b2  = (const float*)d_in[8];
  const float* W3l = (const float*)d_in[9];
  const float* W3r = (const float*)d_in[10];
  const float* b3  = (const float*)d_in[11];
  const float* Wfc = (const float*)d_in[12];
  const float* bfc = (const float*)d_in[13];
  float* out = (float*)d_out;
  int N = in_sizes[0];
  int E = in_sizes[1] / 2;
  const int* src = ei;
  const int* dst = ei + E;

  char* p = (char*)d_ws;
  auto alloc = [&](size_t bytes) { void* r = (void*)p; p += (bytes + 255) & ~(size_t)255; return r; };
  int* roff   = (int*)alloc((size_t)(N + 1) * 4);
  int* csr    = (int*)alloc((size_t)E * 4);
  u32* bufA   = (u32*)alloc((size_t)N * 64 * 4);  // h1 -> mean3 (aliases boff early)
  u32* bufB   = (u32*)alloc((size_t)N * 64 * 4);  // mean2 -> h2 (aliases part early)
  u16* wt2    = (u16*)alloc(32768 * 2);
  u16* wt3    = (u16*)alloc(32768 * 2);
  // pooled/gcnt/btotal contiguous -> single memset below
  float* pooled = (float*)alloc(64 * 128 * 4);    // 32768 B
  int* gcnt   = (int*)alloc(64 * 4);              // 256 B
  int* btotal = (int*)alloc(1024 * 4);            // 4096 B
  int* bbase  = (int*)alloc(1024 * 4);

  // CSR-build-time aliases (boff read only by scatter2; scatter3 writes h1
  // into bufA but reads only bbase/part/x -> no clobber hazard)
  int nbuk = (N + 127) >> 7;          // 782
  int* boff = (int*)bufA;             // HBLK rows x 1024 ints = 1 MB (row-major)
  u32* part = (u32*)bufB;             // E u32 = 6.4 MB
  int chunk = (((E + HBLK - 1) / HBLK) + 3) & ~3;  // 16B-aligned block windows

  hipMemsetAsync(pooled, 0, 32768 + 256 + 4096, stream);  // pooled+gcnt+btotal
  hist_wprep_kernel<<<HBLK, 1024, 0, stream>>>(dst, boff, btotal, E, nbuk, chunk,
                                               W2l, W2r, W3l, W3r, wt2, wt3,
                                               batch, gcnt, N);
  scatter2_kernel<<<HBLK, 1024, 0, stream>>>(src, dst, btotal, boff, part, bbase,
                                             E, nbuk, chunk);
  scatter3_kernel<<<nbuk, 512, 0, stream>>>(part, bbase, x, W1l, W1r, b1,
                                            roff, csr, bufA, E, nbuk, N);
  // layer 2: mean2 = agg(h1); h2 = relu([mean2|h1]W2 + b2) written to bufB
  agg_kernel<<<(N + 15) / 16, 256, 0, stream>>>(csr, roff, bufA, bufB, N);
  mm_kernel<0><<<(N + 127) / 128, 512, 0, stream>>>((const u16*)bufB, (const u16*)bufA,
                                                    wt2, b2, (u16*)bufB, batch, pooled, N);
  // layer 3: mean3 = agg(h2); h3 -> pooled directly (never hits global)
  agg_kernel<<<(N + 15) / 16, 256, 0, stream>>>(csr, roff, bufB, bufA, N);
  mm_kernel<1><<<(N + 127) / 128, 512, 0, stream>>>((const u16*)bufA, (const u16*)bufB,
                                                    wt3, b3, (u16*)bufA, batch, pooled, N);
  head_kernel<<<1, 640, 0, stream>>>(pooled, gcnt, Wfc, bfc, out);
}